// Round 13
// baseline (3722.603 us; speedup 1.0000x reference)
//
#include <hip/hip_runtime.h>

typedef unsigned short u16;
typedef u16 u16x8 __attribute__((ext_vector_type(8)));
typedef __bf16 bf16x8 __attribute__((ext_vector_type(8)));
typedef float f32x4 __attribute__((ext_vector_type(4)));

#define TTOK 32768
#define HD 512
#define FFD 2048
#define SLEN 64
#define EW 262144            // 512*512 elems

__device__ __forceinline__ float b2f(u16 u) {
  union { float f; unsigned int i; } v; v.i = ((unsigned int)u) << 16; return v.f;
}
__device__ __forceinline__ u16 f2b(float f) {
  union { float f; unsigned int i; } v; v.f = f;
  unsigned int i = v.i;
  return (u16)((i + 0x7FFFu + ((i >> 16) & 1u)) >> 16);  // RNE
}

__device__ __forceinline__ void gload16(const u16* g, u16* l) {
  __builtin_amdgcn_global_load_lds((const __attribute__((address_space(1))) void*)g,
                                   (__attribute__((address_space(3))) void*)l,
                                   16, 0, 0);
}

__device__ __forceinline__ f32x4 mfma16(bf16x8 a, bf16x8 b, f32x4 c) {
  return __builtin_amdgcn_mfma_f32_16x16x32_bf16(a, b, c, 0, 0, 0);
}

// ---------------- positional encoding table [S,H] f32 ----------------
__global__ __launch_bounds__(256) void pe_kernel(float* __restrict__ pe) {
  int idx = blockIdx.x * 256 + threadIdx.x;
  int s = idx >> 9, h = idx & 511;
  float e2i = (float)(h & ~1);
  float ang = (float)s * powf(10000.0f, -e2i * (1.0f / 512.0f));
  pe[idx] = (h & 1) ? cosf(ang) : sinf(ang);
}

// ------------- merged weight conversion: all 13 tensors, one launch -------------
struct WArgs {
  const float* src[13];
  unsigned long long dstoff[13];   // elems from W base
  unsigned npl[13];                // elems per layer
  unsigned dstride[13];            // layer stride (elems)
  unsigned cum[14];                // cumulative elem offsets
};

__global__ __launch_bounds__(256) void wconv_all(WArgs a, u16* __restrict__ Wb) {
  unsigned i = ((unsigned)blockIdx.x * 256 + threadIdx.x) * 8;
  int t = 0;
  #pragma unroll
  for (int k = 1; k < 13; ++k) if (i >= a.cum[k]) t = k;
  unsigned local = i - a.cum[t];
  unsigned l = local / a.npl[t];
  unsigned r = local - l * a.npl[t];
  const float* s = a.src[t] + local;
  f32x4 x0 = *(const f32x4*)s, x1 = *(const f32x4*)(s + 4);
  u16x8 o;
  #pragma unroll
  for (int k = 0; k < 4; ++k) { o[k] = f2b(x0[k]); o[4 + k] = f2b(x1[k]); }
  *(u16x8*)(Wb + a.dstoff[t] + (size_t)l * a.dstride[t] + r) = o;
}

// ---------------- embedding (f32) + PE (f32) -> bf16 ----------------
__global__ __launch_bounds__(256) void embed_kernel(
    const int* __restrict__ ids, const float* __restrict__ emb,
    const float* __restrict__ pe, u16* __restrict__ outB) {
  int chunk = blockIdx.x * 256 + threadIdx.x;
  int t = chunk >> 6;
  int c8 = (chunk & 63) * 8;
  int s = t & (SLEN - 1);
  int id = ids[t];
  const float* e = emb + (size_t)id * HD + c8;
  const float* p = pe + s * HD + c8;
  f32x4 e0 = *(const f32x4*)e, e1 = *(const f32x4*)(e + 4);
  f32x4 p0 = *(const f32x4*)p, p1 = *(const f32x4*)(p + 4);
  u16x8 ob;
  #pragma unroll
  for (int i = 0; i < 4; ++i) {
    ob[i]     = f2b(e0[i] + p0[i]);
    ob[4 + i] = f2b(e1[i] + p1[i]);
  }
  *(u16x8*)(outB + (size_t)t * HD + c8) = ob;
}

// ---------------- residual + layernorm (bf16 in, f32 params) ----------------
template<int F32OUT>
__global__ __launch_bounds__(256) void ln_kernel(
    const u16* A, const u16* __restrict__ Z, int ldz,
    const float* __restrict__ g, const float* __restrict__ b,
    u16* outB, float* outF) {
  int row = blockIdx.x * 4 + (threadIdx.x >> 6);
  int lane = threadIdx.x & 63;
  size_t base = (size_t)row * HD + lane * 8;
  size_t zbase = (size_t)row * ldz + lane * 8;
  u16x8 av = *(const u16x8*)(A + base);
  u16x8 zv = *(const u16x8*)(Z + zbase);
  float x[8];
  float s = 0.f;
  #pragma unroll
  for (int i = 0; i < 8; ++i) { x[i] = b2f(av[i]) + b2f(zv[i]); s += x[i]; }
  #pragma unroll
  for (int off = 32; off; off >>= 1) s += __shfl_xor(s, off);
  float m = s * (1.0f / HD);
  float vs = 0.f;
  #pragma unroll
  for (int i = 0; i < 8; ++i) { float d = x[i] - m; vs += d * d; }
  #pragma unroll
  for (int off = 32; off; off >>= 1) vs += __shfl_xor(vs, off);
  float rstd = rsqrtf(vs * (1.0f / HD) + 1e-5f);
  f32x4 g0 = *(const f32x4*)(g + lane * 8), g1 = *(const f32x4*)(g + lane * 8 + 4);
  f32x4 b0 = *(const f32x4*)(b + lane * 8), b1 = *(const f32x4*)(b + lane * 8 + 4);
  float o[8];
  #pragma unroll
  for (int i = 0; i < 4; ++i) {
    o[i]     = (x[i] - m) * rstd * g0[i] + b0[i];
    o[4 + i] = (x[4 + i] - m) * rstd * g1[i] + b1[i];
  }
  if (F32OUT) {
    f32x4 o0, o1;
    #pragma unroll
    for (int i = 0; i < 4; ++i) { o0[i] = o[i]; o1[i] = o[4 + i]; }
    *(f32x4*)(outF + base) = o0;
    *(f32x4*)(outF + base + 4) = o1;
  } else {
    u16x8 ob;
    #pragma unroll
    for (int i = 0; i < 8; ++i) ob[i] = f2b(o[i]);
    *(u16x8*)(outB + base) = ob;
  }
}

#define BAR() __builtin_amdgcn_s_barrier()
#define WAIT_LGKM0() asm volatile("s_waitcnt lgkmcnt(0)" ::: "memory")
#define WAIT_VM8()   asm volatile("s_waitcnt vmcnt(8)" ::: "memory")
#define WAIT_VM3()   asm volatile("s_waitcnt vmcnt(3)" ::: "memory")
#define WAIT_VM2()   asm volatile("s_waitcnt vmcnt(2)" ::: "memory")
#define WAIT_VM0()   asm volatile("s_waitcnt vmcnt(0)" ::: "memory")

// ========== 128x256 bf16 NT GEMM, 48KB LDS double-buffer, 2 blocks/CU ==========
template<int BIAS>
__global__ __launch_bounds__(512, 4) void gemm128(
    const u16* __restrict__ A, const u16* __restrict__ Bw,
    const float* __restrict__ bias, u16* __restrict__ Cb,
    int nbn, int K, int lda, int ldb, int ldc) {
  __shared__ u16 lds[24576];               // 48 KB
  const int tid = threadIdx.x;
  const int lane = tid & 63, w = tid >> 6;
  const int wr = w >> 2, wc = w & 3;
  const int l15 = lane & 15, lq = lane >> 4;

  const int cpx = gridDim.x >> 3;
  const int L = (blockIdx.x & 7) * cpx + (blockIdx.x >> 3);
  const int bm = (L / nbn) * 128, bn = (L % nbn) * 256;

  const u16 *pa, *pb0, *pb1;
  {
    int p = tid * 16;
    int row = p >> 6;
    int lb = ((((p >> 4) & 3) ^ ((row >> 2) & 3)) << 4) | (p & 15);
    pa = A + (size_t)(bm + row) * lda + (lb >> 1);
    int r0 = p >> 6;
    int lb0 = ((((p >> 4) & 3) ^ ((r0 >> 2) & 3)) << 4) | (p & 15);
    pb0 = Bw + (size_t)(bn + r0) * ldb + (lb0 >> 1);
    int p1 = p + 8192;
    int r1 = p1 >> 6;
    int lb1 = ((((p1 >> 4) & 3) ^ ((r1 >> 2) & 3)) << 4) | (p1 & 15);
    pb1 = Bw + (size_t)(bn + r1) * ldb + (lb1 >> 1);
  }

  int offA[4], offB[4];
  #pragma unroll
  for (int mf = 0; mf < 4; ++mf) {
    int row = wr * 64 + mf * 16 + l15;
    offA[mf] = row * 32 + ((lq ^ ((row >> 2) & 3)) << 3);
  }
  #pragma unroll
  for (int j = 0; j < 4; ++j) {
    int row = wc * 64 + j * 16 + l15;
    offB[j] = row * 32 + ((lq ^ ((row >> 2) & 3)) << 3);
  }

  const int NS = K >> 5;

#define STAGE(s, sl) { \
    gload16(pa  + (s) * 32, &lds[(sl) * 4096 + w * 512]); \
    gload16(pb0 + (s) * 32, &lds[8192 + (sl) * 8192 + w * 512]); \
    gload16(pb1 + (s) * 32, &lds[8192 + (sl) * 8192 + w * 512 + 4096]); }

  f32x4 acc[4][4] = {};

  STAGE(0, 0);
  for (int h = 0; h < NS; ++h) {
    int nh = h + 1; if (nh > NS - 1) nh = NS - 1;
    STAGE(nh, (h + 1) & 1);
    WAIT_VM3();
    BAR();
    const int sa = (h & 1) * 4096, sb = 8192 + (h & 1) * 8192;
    bf16x8 af[4], bf4[4];
    #pragma unroll
    for (int i = 0; i < 4; ++i) af[i] = *(const bf16x8*)&lds[sa + offA[i]];
    #pragma unroll
    for (int j = 0; j < 4; ++j) bf4[j] = *(const bf16x8*)&lds[sb + offB[j]];
    WAIT_LGKM0();
    __builtin_amdgcn_s_setprio(1);
    #pragma unroll
    for (int mf = 0; mf < 4; ++mf)
      #pragma unroll
      for (int j = 0; j < 4; ++j)
        acc[mf][j] = mfma16(af[mf], bf4[j], acc[mf][j]);
    __builtin_amdgcn_s_setprio(0);
    BAR();
  }
  WAIT_VM0();

  #pragma unroll
  for (int q = 0; q < 4; ++q) {
    BAR();
    if (wr == (q >> 1)) {
      #pragma unroll
      for (int mi = 0; mi < 2; ++mi) {
        int mf = (q & 1) * 2 + mi;
        #pragma unroll
        for (int j = 0; j < 4; ++j)
          #pragma unroll
          for (int r = 0; r < 4; ++r) {
            int lrow = mi * 16 + lq * 4 + r;
            int col = wc * 64 + j * 16 + l15;
            int byt = (lrow * 1024 + col * 4) ^ (((lrow >> 2) & 3) << 6);
            *(float*)((char*)lds + byt) = acc[mf][j][r];
          }
      }
    }
    WAIT_LGKM0();
    BAR();
    #pragma unroll
    for (int k = 0; k < 2; ++k) {
      int c = tid + k * 512;
      int row = c >> 5, c32 = c & 31;
      int byt = (row * 1024 + c32 * 32) ^ (((row >> 2) & 3) << 6);
      f32x4 v0 = *(const f32x4*)((const char*)lds + byt);
      f32x4 v1 = *(const f32x4*)((const char*)lds + byt + 16);
      int gcol = bn + c32 * 8;
      size_t off = (size_t)(bm + q * 32 + row) * ldc + gcol;
      if (BIAS) {
        f32x4 bb0 = *(const f32x4*)(bias + gcol);
        f32x4 bb1 = *(const f32x4*)(bias + gcol + 4);
        #pragma unroll
        for (int i = 0; i < 4; ++i) { v0[i] += bb0[i]; v1[i] += bb1[i]; }
      }
      u16x8 ob;
      #pragma unroll
      for (int i = 0; i < 4; ++i) { ob[i] = f2b(v0[i]); ob[4 + i] = f2b(v1[i]); }
      *(u16x8*)(Cb + off) = ob;
    }
  }
#undef STAGE
}

// ===================== 256x256 8-phase pipelined bf16 NT GEMM (round-7) ==========
template<int BIAS, int ACC>
__global__ __launch_bounds__(512, 2) void gemm256(
    const u16* __restrict__ A, const u16* __restrict__ Bw,
    const float* __restrict__ bias, u16* __restrict__ Cb,
    int nbn, int K, int lda, int ldb, int ldc) {
  __shared__ u16 lds[65536];               // 128 KB
  const int tid = threadIdx.x;
  const int lane = tid & 63, w = tid >> 6;
  const int wr = w >> 2, wc = w & 3;
  const int l15 = lane & 15, lq = lane >> 4;

  const int cpx = gridDim.x >> 3;
  const int L = (blockIdx.x & 7) * cpx + (blockIdx.x >> 3);
  const int bm = (L / nbn) * 256, bn = (L % nbn) * 256;

  const u16 *pa0, *pa1, *pb0, *pb1;
  {
    int p0 = w * 1024 + lane * 16;
    int p1 = p0 + 8192;
    int lb0 = p0 ^ (((p0 >> 7) & 7) << 4);
    int lb1 = p1 ^ (((p1 >> 7) & 7) << 4);
    int r0 = (lb0 >> 7) + (((lb0 >> 6) & 1) << 7);
    int r1 = (lb1 >> 7) + (((lb1 >> 6) & 1) << 7);
    int c0 = (lb0 & 63) >> 1;
    int c1 = (lb1 & 63) >> 1;
    pa0 = A  + (size_t)(bm + r0) * lda + c0;
    pa1 = A  + (size_t)(bm + r1) * lda + c1;
    pb0 = Bw + (size_t)(bn + r0) * ldb + c0;
    pb1 = Bw + (size_t)(bn + r1) * ldb + c1;
  }
  const int dst = w * 512;

  int offA[8], offB[4];
  #pragma unroll
  for (int mf = 0; mf < 8; ++mf) {
    int rowp = mf * 16 + l15;
    offA[mf] = ((rowp * 128 + wr * 64 + lq * 16) ^ ((l15 & 7) << 4)) >> 1;
  }
  #pragma unroll
  for (int j = 0; j < 4; ++j) {
    int rB = wc * 64 + j * 16 + l15;
    int rowp = rB & 127, cg = rB >> 7;
    offB[j] = ((rowp * 128 + cg * 64 + lq * 16) ^ ((l15 & 7) << 4)) >> 1;
  }

  const int NK2 = K >> 5;
  const int NT  = K >> 6;

#define STAGEA(kh, slot) { \
    gload16(pa0 + (kh) * 32, &lds[(slot) * 8192 + dst]); \
    gload16(pa1 + (kh) * 32, &lds[(slot) * 8192 + dst + 4096]); }
#define STAGEB(kh, slot) { \
    gload16(pb0 + (kh) * 32, &lds[32768 + (slot) * 8192 + dst]); \
    gload16(pb1 + (kh) * 32, &lds[32768 + (slot) * 8192 + dst + 4096]); }
#define LDA4(slot, mh) { \
    _Pragma("unroll") for (int i = 0; i < 4; ++i) \
      af[i] = *(const bf16x8*)&lds[(slot) * 8192 + offA[(mh) * 4 + i]]; }
#define LDB4(slot) { \
    _Pragma("unroll") for (int j = 0; j < 4; ++j) \
      bf[j] = *(const bf16x8*)&lds[32768 + (slot) * 8192 + offB[j]]; }
#define MFMA16(mh) { \
    __builtin_amdgcn_s_setprio(1); \
    _Pragma("unroll") for (int i = 0; i < 4; ++i) \
      _Pragma("unroll") for (int j = 0; j < 4; ++j) \
        acc[(mh) * 4 + i][j] = mfma16(af[i], bf[j], acc[(mh) * 4 + i][j]); \
    __builtin_amdgcn_s_setprio(0); }

  f32x4 acc[8][4] = {};
  bf16x8 af[4], bf[4];

  STAGEA(0, 0); STAGEB(0, 0);
  STAGEA(1, 1); STAGEB(1, 1);
  STAGEA(2, 2); STAGEB(2, 2);
  WAIT_VM8();
  BAR();

  for (int t = 0; t < NT; ++t) {
    const int s0 = (2 * t) & 3, s1 = (2 * t + 1) & 3;
    int kh3 = 2 * t + 3; if (kh3 > NK2 - 1) kh3 = NK2 - 1;
    int kh4 = 2 * t + 4; if (kh4 > NK2 - 1) kh4 = NK2 - 1;
    const int w3 = (2 * t + 3) & 3, w4 = (2 * t + 4) & 3;

    LDB4(s0); LDA4(s0, 0);
    STAGEA(kh3, w3);
    BAR(); WAIT_LGKM0();
    MFMA16(0);
    BAR();

    LDA4(s0, 1);
    STAGEB(kh3, w3);
    BAR(); WAIT_LGKM0();
    MFMA16(1);
    WAIT_VM8();
    BAR();

    LDB4(s1); LDA4(s1, 0);
    STAGEA(kh4, w4);
    BAR(); WAIT_LGKM0();
    MFMA16(0);
    BAR();

    LDA4(s1, 1);
    STAGEB(kh4, w4);
    BAR(); WAIT_LGKM0();
    MFMA16(1);
    WAIT_VM8();
    BAR();
  }
  WAIT_VM0();

  #pragma unroll
  for (int h = 0; h < 2; ++h) {
    BAR();
    if (wr == h) {
      #pragma unroll
      for (int mf = 0; mf < 8; ++mf)
        #pragma unroll
        for (int j = 0; j < 4; ++j)
          #pragma unroll
          for (int r = 0; r < 4; ++r) {
            int row = mf * 16 + lq * 4 + r;
            int col = wc * 64 + j * 16 + l15;
            int byt = (row * 1024 + col * 4) ^ (((row >> 2) & 1) << 6);
            *(float*)((char*)lds + byt) = acc[mf][j][r];
          }
    }
    WAIT_LGKM0();
    BAR();
    #pragma unroll
    for (int k = 0; k < 8; ++k) {
      int c = tid + k * 512;
      int row = c >> 5, c32 = c & 31;
      int byt = (row * 1024 + c32 * 32) ^ (((row >> 2) & 1) << 6);
      f32x4 v0 = *(const f32x4*)((const char*)lds + byt);
      f32x4 v1 = *(const f32x4*)((const char*)lds + byt + 16);
      int gcol = bn + c32 * 8;
      size_t off = (size_t)(bm + h * 128 + row) * ldc + gcol;
      if (BIAS) {
        f32x4 bb0 = *(const f32x4*)(bias + gcol);
        f32x4 bb1 = *(const f32x4*)(bias + gcol + 4);
        #pragma unroll
        for (int i = 0; i < 4; ++i) { v0[i] += bb0[i]; v1[i] += bb1[i]; }
      }
      u16x8 ob;
      if (ACC) {
        u16x8 cr = *(const u16x8*)(Cb + off);
        #pragma unroll
        for (int i = 0; i < 4; ++i) {
          ob[i]     = f2b(v0[i] + b2f(cr[i]));
          ob[4 + i] = f2b(v1[i] + b2f(cr[4 + i]));
        }
      } else {
        #pragma unroll
        for (int i = 0; i < 4; ++i) { ob[i] = f2b(v0[i]); ob[4 + i] = f2b(v1[i]); }
      }
      *(u16x8*)(Cb + off) = ob;
    }
  }
#undef STAGEA
#undef STAGEB
#undef LDA4
#undef LDB4
#undef MFMA16
}

// ========== 128x512 GEMM + residual + LayerNorm fused, 16 waves, 4 w/SIMD ==========
// out = LN(resid + A@Bw^T (+bias)); block owns 128 FULL rows; grid 256.
// 16 waves (2M x 8N): wave w = (wr=w>>3)*64 rows x (wc=w&7)*64 cols -> acc[4][4].
// BK=32 double-buffer, LDS 80KB: A 2x8KB @0, B 2x32KB @16KB (gemm128 swizzle).
// Staging per step: B = 2 gloads x 1024 thr; A = +1 gload for waves 0-7 ->
// counted vmcnt 3/2. Epilogue: 4 passes x 32 rows f32 LDS staging, 2 rows/wave
// shfl LN, vectorized stores (math identical to round-9 gemm_ln).
template<int BIAS, int F32OUT>
__global__ __launch_bounds__(1024, 4) void gemm_ln16(
    const u16* __restrict__ A, const u16* __restrict__ Bw,
    const float* __restrict__ bias,
    const u16* __restrict__ resid, const float* __restrict__ g,
    const float* __restrict__ bv,
    u16* outB, float* outF, int K, int lda, int ldb) {
  __shared__ u16 lds[40960];               // 80 KB
  const int tid = threadIdx.x;
  const int lane = tid & 63, w = tid >> 6;   // w 0..15
  const int wr = w >> 3, wc = w & 7;
  const int l15 = lane & 15, lq = lane >> 4;

  const int cpx = gridDim.x >> 3;
  const int L = (blockIdx.x & 7) * cpx + (blockIdx.x >> 3);
  const int bm = L * 128;

  // staging sources (pre-swizzled; 16B-slot swizzle within 64B rows)
  const u16 *pa, *pb0, *pb1;
  {
    int p = (tid * 16) & 8191;             // byte in 8KB A slot (waves 0-7 use)
    int row = p >> 6;                      // 0..127
    int lb = ((((p >> 4) & 3) ^ ((row >> 2) & 3)) << 4) | (p & 15);
    pa = A + (size_t)(bm + row) * lda + (lb >> 1);
    int q0 = tid * 16;                     // byte in 32KB B slot, seg 0
    int r0 = q0 >> 6;                      // 0..511
    int lb0 = ((((q0 >> 4) & 3) ^ ((r0 >> 2) & 3)) << 4) | (q0 & 15);
    pb0 = Bw + (size_t)r0 * ldb + (lb0 >> 1);
    int q1 = q0 + 16384;                   // seg 1 (second 16KB half)
    int r1 = q1 >> 6;
    int lb1 = ((((q1 >> 4) & 3) ^ ((r1 >> 2) & 3)) << 4) | (q1 & 15);
    pb1 = Bw + (size_t)r1 * ldb + (lb1 >> 1);
  }

  // fragment ds_read element offsets (within slot)
  int offA[4], offB[4];
  #pragma unroll
  for (int mf = 0; mf < 4; ++mf) {
    int row = wr * 64 + mf * 16 + l15;     // 0..127
    offA[mf] = row * 32 + ((lq ^ ((row >> 2) & 3)) << 3);
  }
  #pragma unroll
  for (int j = 0; j < 4; ++j) {
    int row = wc * 64 + j * 16 + l15;      // 0..511
    offB[j] = row * 32 + ((lq ^ ((row >> 2) & 3)) << 3);
  }

  const int NS = K >> 5;

  // LDS elems: A slots @0/4096 (4096 each); B slots @8192 + sl*16384 (16384 each)
#define STAGE(s, sl) { \
    if (w < 8) gload16(pa + (s) * 32, &lds[(sl) * 4096 + w * 512]); \
    gload16(pb0 + (s) * 32, &lds[8192 + (sl) * 16384 + w * 512]); \
    gload16(pb1 + (s) * 32, &lds[8192 + (sl) * 16384 + 8192 + w * 512]); }

  f32x4 acc[4][4] = {};

  STAGE(0, 0);
  for (int h = 0; h < NS; ++h) {
    int nh = h + 1; if (nh > NS - 1) nh = NS - 1;
    STAGE(nh, (h + 1) & 1);
    if (w < 8) { WAIT_VM3(); } else { WAIT_VM2(); }
    BAR();
    const int sa = (h & 1) * 4096, sb = 8192 + (h & 1) * 16384;
    bf16x8 af[4], bf4[4];
    #pragma unroll
    for (int i = 0; i < 4; ++i) af[i] = *(const bf16x8*)&lds[sa + offA[i]];
    #pragma unroll
    for (int j = 0; j < 4; ++j) bf4[j] = *(const bf16x8*)&lds[sb + offB[j]];
    WAIT_LGKM0();
    __builtin_amdgcn_s_setprio(1);
    #pragma unroll
    for (int mf = 0; mf < 4; ++mf)
      #pragma unroll
      for (int j = 0; j < 4; ++j)
        acc[mf][j] = mfma16(af[mf], bf4[j], acc[mf][j]);
    __builtin_amdgcn_s_setprio(0);
    BAR();
  }
  WAIT_VM0();

  // hoisted per-lane constants
  float bias4[4] = {0.f, 0.f, 0.f, 0.f};
  if (BIAS) {
    #pragma unroll
    for (int j = 0; j < 4; ++j) bias4[j] = bias[wc * 64 + j * 16 + l15];
  }
  const f32x4 gv0 = *(const f32x4*)(g + lane * 8);
  const f32x4 gv1 = *(const f32x4*)(g + lane * 8 + 4);
  const f32x4 bv0 = *(const f32x4*)(bv + lane * 8);
  const f32x4 bv1 = *(const f32x4*)(bv + lane * 8 + 4);

  // ---- epilogue: 4 passes of 32 rows (64 KB f32 staging) + fused LN ----
  #pragma unroll
  for (int q = 0; q < 4; ++q) {
    BAR();
    if (wr == (q >> 1)) {
      #pragma unroll
      for (int mi = 0; mi < 2; ++mi) {
        int mf = (q & 1) * 2 + mi;
        #pragma unroll
        for (int j = 0; j < 4; ++j)
          #pragma unroll
          for (int r = 0; r < 4; ++r) {
            int lrow = mi * 16 + lq * 4 + r;               // 0..31
            int col = wc * 64 + j * 16 + l15;              // 0..511
            int byt = (lrow * 2048 + col * 4) ^ (((lrow >> 2) & 3) << 6);
            *(float*)((char*)lds + byt) = acc[mf][j][r] + bias4[j];
          }
      }
    }
    WAIT_LGKM0();
    BAR();
    // wave w handles rows lrow = w*2, w*2+1
    #pragma unroll
    for (int rr = 0; rr < 2; ++rr) {
      int lrow = w * 2 + rr;
      int grow = bm + q * 32 + lrow;
      int byt = (lrow * 2048 + lane * 32) ^ (((lrow >> 2) & 3) << 6);
      f32x4 z0 = *(const f32x4*)((const char*)lds + byt);
      f32x4 z1 = *(const f32x4*)((const char*)lds + byt + 16);
      u16x8 av = *(const u16x8*)(resid + (size_t)grow * HD + lane * 8);
      float x[8];
      float s = 0.f;
      #pragma unroll
      for (int i = 0; i < 4; ++i) {
        x[i] = b2f(av[i]) + z0[i];
        x[4 + i] = b2f(av[4 + i]) + z1[i];
      }
      #pragma unroll
      for (int i = 0; i < 8; ++i) s += x[i];
      #pragma unroll
      for (int off = 32; off; off >>= 1) s += __shfl_xor(s, off);
      float m = s * (1.0f / HD);
      float vs = 0.f;
      #pragma unroll
      for (int i = 0; i < 8; ++i) { float d = x[i] - m; vs += d * d; }
      #pragma unroll
      for (int off = 32; off; off >>= 1) vs += __shfl_xor(vs, off);
      float rstd = rsqrtf(vs * (1.0f / HD) + 1e-5f);
      float o[8];
      #pragma unroll
      for (int i = 0; i < 4; ++i) {
        o[i]     = (x[i] - m) * rstd * gv0[i] + bv0[i];
        o[4 + i] = (x[4 + i] - m) * rstd * gv1[i] + bv1[i];
      }
      if (F32OUT) {
        f32x4 o0, o1;
        #pragma unroll
        for (int i = 0; i < 4; ++i) { o0[i] = o[i]; o1[i] = o[4 + i]; }
        *(f32x4*)(outF + (size_t)grow * HD + lane * 8) = o0;
        *(f32x4*)(outF + (size_t)grow * HD + lane * 8 + 4) = o1;
      } else {
        u16x8 ob;
        #pragma unroll
        for (int i = 0; i < 8; ++i) ob[i] = f2b(o[i]);
        *(u16x8*)(outB + (size_t)grow * HD + lane * 8) = ob;
      }
    }
  }
#undef STAGE
}

// ---------------- attention: one block per (b, head), S=64, DK=64 ----------------
template<int CAUSAL, int SAVEKV>
__global__ __launch_bounds__(256) void attn_kernel(
    u16* Q, const u16* __restrict__ Kb, const u16* __restrict__ Vb,
    const int* __restrict__ mask, int qld, int kvld, u16* __restrict__ kvdst) {
  __shared__ u16 Ks[64 * 72];
  __shared__ u16 Vt[64 * 72];
  __shared__ u16 Ps[4][16 * 72];
  const int bh = blockIdx.x;
  const int b = bh >> 3, h = bh & 7;
  const int h0 = h * 64;
  const int tid = threadIdx.x, lane = tid & 63, w = tid >> 6;
  const size_t qbase = (size_t)b * 64 * qld + h0;
  const size_t kbase = (size_t)b * 64 * kvld + h0;
  const int l15 = lane & 15, l16 = (lane >> 4) * 8;

  {
    int r = tid >> 2;
    int c = (tid & 3) * 16;
    const u16* ksrc = Kb + kbase + (size_t)r * kvld + c;
    u16x8 k0 = *(const u16x8*)ksrc;
    u16x8 k1 = *(const u16x8*)(ksrc + 8);
    *(u16x8*)&Ks[r * 72 + c]     = k0;
    *(u16x8*)&Ks[r * 72 + c + 8] = k1;
    const u16* vsrc = Vb + kbase + (size_t)r * kvld + c;
    u16x8 t0 = *(const u16x8*)vsrc;
    u16x8 t1 = *(const u16x8*)(vsrc + 8);
    #pragma unroll
    for (int i = 0; i < 8; ++i) {
      Vt[(c + i) * 72 + r]     = t0[i];
      Vt[(c + 8 + i) * 72 + r] = t1[i];
    }
    if (SAVEKV) {
      size_t db = (size_t)(b * 64 + r) * 1024 + h0 + c;
      *(u16x8*)(kvdst + db)       = k0;
      *(u16x8*)(kvdst + db + 8)   = k1;
      *(u16x8*)(kvdst + db + 512) = t0;
      *(u16x8*)(kvdst + db + 520) = t1;
    }
  }
  const int qrow = w * 16 + l15;
  const u16* qp = Q + qbase + (size_t)qrow * qld;
  bf16x8 qf0 = *(const bf16x8*)&qp[l16];
  bf16x8 qf1 = *(const bf16x8*)&qp[32 + l16];
  __syncthreads();

  f32x4 sc[4] = {};
  #pragma unroll
  for (int nf = 0; nf < 4; ++nf) {
    bf16x8 k0 = *(const bf16x8*)&Ks[(nf * 16 + l15) * 72 + l16];
    bf16x8 k1 = *(const bf16x8*)&Ks[(nf * 16 + l15) * 72 + 32 + l16];
    sc[nf] = mfma16(qf0, k0, sc[nf]);
    sc[nf] = mfma16(qf1, k1, sc[nf]);
  }
  int mk[4];
  #pragma unroll
  for (int nf = 0; nf < 4; ++nf) mk[nf] = mask[b * 64 + nf * 16 + l15];
  float pv[4][4];
  #pragma unroll
  for (int r = 0; r < 4; ++r) {
    int q = w * 16 + (lane >> 4) * 4 + r;
    #pragma unroll
    for (int nf = 0; nf < 4; ++nf) {
      int k = nf * 16 + l15;
      bool kp = (mk[nf] != 0);
      if (CAUSAL) kp = kp && (k <= q);
      pv[r][nf] = kp ? sc[nf][r] * 0.125f : -1e9f;
    }
  }
  #pragma unroll
  for (int r = 0; r < 4; ++r) {
    float mx = fmaxf(fmaxf(pv[r][0], pv[r][1]), fmaxf(pv[r][2], pv[r][3]));
    #pragma unroll
    for (int off = 1; off < 16; off <<= 1) mx = fmaxf(mx, __shfl_xor(mx, off));
    float sum = 0.f;
    #pragma unroll
    for (int nf = 0; nf < 4; ++nf) { pv[r][nf] = __expf(pv[r][nf] - mx); sum += pv[r][nf]; }
    #pragma unroll
    for (int off = 1; off < 16; off <<= 1) sum += __shfl_xor(sum, off);
    float inv = 1.0f / sum;
    #pragma unroll
    for (int nf = 0; nf < 4; ++nf) pv[r][nf] *= inv;
  }
  #pragma unroll
  for (int r = 0; r < 4; ++r) {
    int q = (lane >> 4) * 4 + r;
    #pragma unroll
    for (int nf = 0; nf < 4; ++nf)
      Ps[w][q * 72 + nf * 16 + l15] = f2b(pv[r][nf]);
  }
  f32x4 oacc[4] = {};
  #pragma unroll
  for (int kk = 0; kk < 2; ++kk) {
    bf16x8 pa = *(const bf16x8*)&Ps[w][l15 * 72 + kk * 32 + l16];
    #pragma unroll
    for (int df = 0; df < 4; ++df) {
      bf16x8 vf = *(const bf16x8*)&Vt[(df * 16 + l15) * 72 + kk * 32 + l16];
      oacc[df] = mfma16(pa, vf, oacc[df]);
    }
  }
  #pragma unroll
  for (int df = 0; df < 4; ++df) {
    int col = df * 16 + l15;
    #pragma unroll
    for (int r = 0; r < 4; ++r) {
      int t = w * 16 + (lane >> 4) * 4 + r;
      Q[qbase + (size_t)t * qld + col] = f2b(oacc[df][r]);
    }
  }
}

// ---------------- host side ----------------
extern "C" void kernel_launch(void* const* d_in, const int* in_sizes, int n_in,
                              void* d_out, int out_size, void* d_ws, size_t ws_size,
                              hipStream_t stream) {
  const int* src_ids    = (const int*)d_in[0];
  const int* tgt_ids    = (const int*)d_in[1];
  const int* src_mask   = (const int*)d_in[2];
  const int* tgt_mask   = (const int*)d_in[3];
  const float* src_emb  = (const float*)d_in[4];
  const float* tgt_emb  = (const float*)d_in[5];
  const float* enc_wq = (const float*)d_in[6];
  const float* enc_wk = (const float*)d_in[7];
  const float* enc_wv = (const float*)d_in[8];
  const float* enc_wo = (const float*)d_in[9];
  const float* enc_g  = (const float*)d_in[10];
  const float* enc_b  = (const float*)d_in[11];
  const float* fc1w = (const float*)d_in[12];
  const float* fc1b = (const float*)d_in[13];
  const float* fc2w = (const float*)d_in[14];
  const float* fc2b = (const float*)d_in[15];
  const float* mwq = (const float*)d_in[16];
  const float* mwk = (const float*)d_in[17];
  const float* mwv = (const float*)d_in[18];
  const float* mwo = (const float*)d_in[19];
  const float* cwq = (const float*)d_in[20];
  const float* cwo = (const float*)d_in[21];
  const float* dec_g = (const float*)d_in[22];
  const float* dec_b = (const float*)d_in[23];
  const float* dfw = (const float*)d_in[24];
  const float* dfb = (const float*)d_in[25];
  float* outF = (float*)d_out;
  u16* kvenc = (u16*)d_out;

  constexpr size_t SZ_PE  = (size_t)SLEN * HD * 4;
  constexpr size_t SZ_W   = (size_t)114 * EW * 2;
  constexpr size_t SZ_CUR = (size_t)TTOK * HD * 2;
  constexpr size_t SZ_QKV = (size_t)TTOK * 1536 * 2;
  constexpr size_t SZ_R   = (size_t)TTOK * FFD * 2;
  constexpr size_t SZ_Z2  = (size_t)TTOK * HD * 2;
  constexpr size_t NEED_SMALL = SZ_PE + SZ_W + SZ_CUR + SZ_QKV;
  constexpr size_t NEED_BIG   = SZ_PE + SZ_W + SZ_CUR + SZ_R + SZ_Z2;
  if (ws_size < NEED_SMALL) return;
  const bool big = (ws_size >= NEED_BIG);

  char* ws = (char*)d_ws;
  float* pe = (float*)ws;
  u16* W    = (u16*)(ws + SZ_PE);
  u16* cur  = (u16*)(ws + SZ_PE + SZ_W);
  u16* qkv  = (u16*)(ws + SZ_PE + SZ_W + SZ_CUR);
  u16* z2   = big ? (u16*)(ws + SZ_PE + SZ_W + SZ_CUR + SZ_R)
                  : qkv + (size_t)TTOK * 1024;

  dim3 blk(256), blk5(512), blkX(1024);
  const unsigned int E = EW, S_E = 12 * EW, S_D = 7 * EW;
  u16* WD = W + (size_t)72 * EW;

  pe_kernel<<<128, blk, 0, stream>>>(pe);

  // merged weight conversion (identical layout to the original 13 launches)
  {
    WArgs wa;
    const float* srcs[13] = {enc_wq, enc_wk, enc_wv, enc_wo, fc1w, fc2w,
                             mwq, mwk, mwv, mwo, cwq, cwo, dfw};
    const unsigned long long dstoffs[13] = {
        0ull, (unsigned long long)E, 2ull * E, 3ull * E, 4ull * E, 8ull * E,
        72ull * E, 73ull * E, 74ull * E, 75ull * E, 76ull * E, 77ull * E, 78ull * E};
    const unsigned npls[13] = {E, E, E, E, 4 * E, 4 * E, E, E, E, E, E, E, E};
    const unsigned cumsE[14] = {0, 6, 12, 18, 24, 48, 72, 78, 84, 90, 96, 102, 108, 114};
    for (int t = 0; t < 13; ++t) {
      wa.src[t] = srcs[t];
      wa.dstoff[t] = dstoffs[t];
      wa.npl[t] = npls[t];
      wa.dstride[t] = (t < 6) ? S_E : S_D;
    }
    for (int t = 0; t < 14; ++t) wa.cum[t] = cumsE[t] * E;
    wconv_all<<<14592, blk, 0, stream>>>(wa, W);
  }

  // ---------------- encoder ----------------
  embed_kernel<<<8192, blk, 0, stream>>>(src_ids, src_emb, pe, cur);
  for (int l = 0; l < 6; ++l) {
    const u16* Wl = W + (size_t)l * S_E;
    const float* g  = enc_g + (size_t)l * HD;
    const float* bb = enc_b + (size_t)l * HD;
    const float* b1 = fc1b + (size_t)l * FFD;
    const float* b2 = fc2b + (size_t)l * HD;

    gemm128<0><<<1536, blk5, 0, stream>>>(cur, Wl, nullptr, qkv, 6, 512, 512, 512, 1536);
    if (l == 5)
      attn_kernel<0,1><<<4096, blk, 0, stream>>>(qkv, qkv + 512, qkv + 1024, src_mask, 1536, 1536, kvenc);
    else
      attn_kernel<0,0><<<4096, blk, 0, stream>>>(qkv, qkv + 512, qkv + 1024, src_mask, 1536, 1536, nullptr);
    if (big) {
      gemm_ln16<0,0><<<256, blkX, 0, stream>>>(qkv, Wl + 3 * E, nullptr, cur, g, bb, cur, nullptr, 512, 1536, 512);
      gemm128<1><<<2048, blk5, 0, stream>>>(cur, Wl + 4 * E, b1, qkv, 8, 512, 512, 512, 2048);
      gemm_ln16<1,0><<<256, blkX, 0, stream>>>(qkv, Wl + 8 * E, b2, cur, g, bb, cur, nullptr, 2048, 2048, 2048);
    } else {
      gemm256<0,0><<<256, blk5, 0, stream>>>(qkv, Wl + 3 * E, nullptr, qkv + 1024, 2, 512, 1536, 512, 1536);
      ln_kernel<0><<<8192, blk, 0, stream>>>(cur, qkv + 1024, 1536, g, bb, cur, nullptr);
      gemm256<1,0><<<512, blk5, 0, stream>>>(cur, Wl + 4 * E, b1,        qkv, 4, 512, 512, 512, 1024);
      gemm256<1,0><<<256, blk5, 0, stream>>>(qkv, Wl + 8 * E, b2,        z2,  2, 1024, 1024, 2048, 512);
      gemm256<1,0><<<512, blk5, 0, stream>>>(cur, Wl + 6 * E, b1 + 1024, qkv, 4, 512, 512, 512, 1024);
      gemm256<0,1><<<256, blk5, 0, stream>>>(qkv, Wl + 8 * E + 1024, nullptr, z2, 2, 1024, 1024, 2048, 512);
      ln_kernel<0><<<8192, blk, 0, stream>>>(cur, z2, 512, g, bb, cur, nullptr);
    }
  }

  // ---------------- decoder ----------------
  embed_kernel<<<8192, blk, 0, stream>>>(tgt_ids, tgt_emb, pe, cur);
  for (int l = 0; l < 6; ++l) {
    const u16* Wl = WD + (size_t)l * S_D;
    const float* g  = dec_g + (size_t)l * HD;
    const float* bb = dec_b + (size_t)l * HD;
    const float* fb = dfb + (size_t)l * HD;

    gemm128<0><<<1536, blk5, 0, stream>>>(cur, Wl, nullptr, qkv, 6, 512, 512, 512, 1536);
    attn_kernel<1,0><<<4096, blk, 0, stream>>>(qkv, qkv + 512, qkv + 1024, tgt_mask, 1536, 1536, nullptr);
    if (big) {
      gemm_ln16<0,0><<<256, blkX, 0, stream>>>(qkv, Wl + 3 * E, nullptr, cur, g, bb, cur, nullptr, 512, 1536, 512);
      gemm128<0><<<512, blk5, 0, stream>>>(cur, Wl + 4 * E, nullptr, qkv, 2, 512, 512, 512, 1536);
      attn_kernel<1,0><<<4096, blk, 0, stream>>>(qkv, kvenc, kvenc + 512, tgt_mask, 1536, 1024, nullptr);
      gemm_ln16<0,0><<<256, blkX, 0, stream>>>(qkv, Wl + 5 * E, nullptr, cur, g, bb, cur, nullptr, 512, 1536, 512);
      if (l == 5)
        gemm_ln16<1,1><<<256, blkX, 0, stream>>>(cur, Wl + 6 * E, fb, cur, g, bb, nullptr, outF, 512, 512, 512);
      else
        gemm_ln16<1,0><<<256, blkX, 0, stream>>>(cur, Wl + 6 * E, fb, cur, g, bb, cur, nullptr, 512, 512, 512);
    } else {
      gemm256<0,0><<<256, blk5, 0, stream>>>(qkv, Wl + 3 * E, nullptr, qkv + 1024, 2, 512, 1536, 512, 1536);
      ln_kernel<0><<<8192, blk, 0, stream>>>(cur, qkv + 1024, 1536, g, bb, cur, nullptr);
      gemm256<0,0><<<256, blk5, 0, stream>>>(cur, Wl + 4 * E, nullptr, qkv, 2, 512, 512, 512, 1536);
      attn_kernel<1,0><<<4096, blk, 0, stream>>>(qkv, kvenc, kvenc + 512, tgt_mask, 1536, 1024, nullptr);
      gemm256<0,0><<<256, blk5, 0, stream>>>(qkv, Wl + 5 * E, nullptr, qkv + 1024, 2, 512, 1536, 512, 1536);
      ln_kernel<0><<<8192, blk, 0, stream>>>(cur, qkv + 1024, 1536, g, bb, cur, nullptr);
      gemm256<1,0><<<256, blk5, 0, stream>>>(cur, Wl + 6 * E, fb, qkv, 2, 512, 512, 512, 512);
      if (l == 5)
        ln_kernel<1><<<8192, blk, 0, stream>>>(cur, qkv, 512, g, bb, nullptr, outF);
      else
        ln_kernel<0><<<8192, blk, 0, stream>>>(cur, qkv, 512, g, bb, cur, nullptr);
    }
  }
  (void)in_sizes; (void)n_in; (void)out_size;
}

// Round 14
// 3331.157 us; speedup vs baseline: 1.1175x; 1.1175x over previous
//
#include <hip/hip_runtime.h>

typedef unsigned short u16;
typedef u16 u16x8 __attribute__((ext_vector_type(8)));
typedef __bf16 bf16x8 __attribute__((ext_vector_type(8)));
typedef float f32x4 __attribute__((ext_vector_type(4)));

#define TTOK 32768
#define HD 512
#define FFD 2048
#define SLEN 64
#define EW 262144            // 512*512 elems

__device__ __forceinline__ float b2f(u16 u) {
  union { float f; unsigned int i; } v; v.i = ((unsigned int)u) << 16; return v.f;
}
__device__ __forceinline__ u16 f2b(float f) {
  union { float f; unsigned int i; } v; v.f = f;
  unsigned int i = v.i;
  return (u16)((i + 0x7FFFu + ((i >> 16) & 1u)) >> 16);  // RNE
}

__device__ __forceinline__ void gload16(const u16* g, u16* l) {
  __builtin_amdgcn_global_load_lds((const __attribute__((address_space(1))) void*)g,
                                   (__attribute__((address_space(3))) void*)l,
                                   16, 0, 0);
}

__device__ __forceinline__ f32x4 mfma16(bf16x8 a, bf16x8 b, f32x4 c) {
  return __builtin_amdgcn_mfma_f32_16x16x32_bf16(a, b, c, 0, 0, 0);
}

// ---------------- positional encoding table [S,H] f32 ----------------
__global__ __launch_bounds__(256) void pe_kernel(float* __restrict__ pe) {
  int idx = blockIdx.x * 256 + threadIdx.x;
  int s = idx >> 9, h = idx & 511;
  float e2i = (float)(h & ~1);
  float ang = (float)s * powf(10000.0f, -e2i * (1.0f / 512.0f));
  pe[idx] = (h & 1) ? cosf(ang) : sinf(ang);
}

// ------------- merged weight conversion: all 13 tensors, one launch -------------
struct WArgs {
  const float* src[13];
  unsigned long long dstoff[13];   // elems from W base
  unsigned npl[13];                // elems per layer
  unsigned dstride[13];            // layer stride (elems)
  unsigned cum[14];                // cumulative elem offsets
};

__global__ __launch_bounds__(256) void wconv_all(WArgs a, u16* __restrict__ Wb) {
  unsigned i = ((unsigned)blockIdx.x * 256 + threadIdx.x) * 8;
  int t = 0;
  #pragma unroll
  for (int k = 1; k < 13; ++k) if (i >= a.cum[k]) t = k;
  unsigned local = i - a.cum[t];
  unsigned l = local / a.npl[t];
  unsigned r = local - l * a.npl[t];
  const float* s = a.src[t] + local;
  f32x4 x0 = *(const f32x4*)s, x1 = *(const f32x4*)(s + 4);
  u16x8 o;
  #pragma unroll
  for (int k = 0; k < 4; ++k) { o[k] = f2b(x0[k]); o[4 + k] = f2b(x1[k]); }
  *(u16x8*)(Wb + a.dstoff[t] + (size_t)l * a.dstride[t] + r) = o;
}

// ---------------- embedding (f32) + PE (f32) -> bf16 ----------------
__global__ __launch_bounds__(256) void embed_kernel(
    const int* __restrict__ ids, const float* __restrict__ emb,
    const float* __restrict__ pe, u16* __restrict__ outB) {
  int chunk = blockIdx.x * 256 + threadIdx.x;
  int t = chunk >> 6;
  int c8 = (chunk & 63) * 8;
  int s = t & (SLEN - 1);
  int id = ids[t];
  const float* e = emb + (size_t)id * HD + c8;
  const float* p = pe + s * HD + c8;
  f32x4 e0 = *(const f32x4*)e, e1 = *(const f32x4*)(e + 4);
  f32x4 p0 = *(const f32x4*)p, p1 = *(const f32x4*)(p + 4);
  u16x8 ob;
  #pragma unroll
  for (int i = 0; i < 4; ++i) {
    ob[i]     = f2b(e0[i] + p0[i]);
    ob[4 + i] = f2b(e1[i] + p1[i]);
  }
  *(u16x8*)(outB + (size_t)t * HD + c8) = ob;
}

// ---------------- residual + layernorm (bf16 in, f32 params) ----------------
template<int F32OUT>
__global__ __launch_bounds__(256) void ln_kernel(
    const u16* A, const u16* __restrict__ Z, int ldz,
    const float* __restrict__ g, const float* __restrict__ b,
    u16* outB, float* outF) {
  int row = blockIdx.x * 4 + (threadIdx.x >> 6);
  int lane = threadIdx.x & 63;
  size_t base = (size_t)row * HD + lane * 8;
  size_t zbase = (size_t)row * ldz + lane * 8;
  u16x8 av = *(const u16x8*)(A + base);
  u16x8 zv = *(const u16x8*)(Z + zbase);
  float x[8];
  float s = 0.f;
  #pragma unroll
  for (int i = 0; i < 8; ++i) { x[i] = b2f(av[i]) + b2f(zv[i]); s += x[i]; }
  #pragma unroll
  for (int off = 32; off; off >>= 1) s += __shfl_xor(s, off);
  float m = s * (1.0f / HD);
  float vs = 0.f;
  #pragma unroll
  for (int i = 0; i < 8; ++i) { float d = x[i] - m; vs += d * d; }
  #pragma unroll
  for (int off = 32; off; off >>= 1) vs += __shfl_xor(vs, off);
  float rstd = rsqrtf(vs * (1.0f / HD) + 1e-5f);
  f32x4 g0 = *(const f32x4*)(g + lane * 8), g1 = *(const f32x4*)(g + lane * 8 + 4);
  f32x4 b0 = *(const f32x4*)(b + lane * 8), b1 = *(const f32x4*)(b + lane * 8 + 4);
  float o[8];
  #pragma unroll
  for (int i = 0; i < 4; ++i) {
    o[i]     = (x[i] - m) * rstd * g0[i] + b0[i];
    o[4 + i] = (x[4 + i] - m) * rstd * g1[i] + b1[i];
  }
  if (F32OUT) {
    f32x4 o0, o1;
    #pragma unroll
    for (int i = 0; i < 4; ++i) { o0[i] = o[i]; o1[i] = o[4 + i]; }
    *(f32x4*)(outF + base) = o0;
    *(f32x4*)(outF + base + 4) = o1;
  } else {
    u16x8 ob;
    #pragma unroll
    for (int i = 0; i < 8; ++i) ob[i] = f2b(o[i]);
    *(u16x8*)(outB + base) = ob;
  }
}

#define BAR() __builtin_amdgcn_s_barrier()
#define WAIT_LGKM0() asm volatile("s_waitcnt lgkmcnt(0)" ::: "memory")
#define WAIT_VM8()   asm volatile("s_waitcnt vmcnt(8)" ::: "memory")
#define WAIT_VM5()   asm volatile("s_waitcnt vmcnt(5)" ::: "memory")
#define WAIT_VM3()   asm volatile("s_waitcnt vmcnt(3)" ::: "memory")
#define WAIT_VM0()   asm volatile("s_waitcnt vmcnt(0)" ::: "memory")

// ========== 128x256 bf16 NT GEMM, 48KB LDS double-buffer, 2 blocks/CU ==========
template<int BIAS>
__global__ __launch_bounds__(512, 4) void gemm128(
    const u16* __restrict__ A, const u16* __restrict__ Bw,
    const float* __restrict__ bias, u16* __restrict__ Cb,
    int nbn, int K, int lda, int ldb, int ldc) {
  __shared__ u16 lds[24576];               // 48 KB
  const int tid = threadIdx.x;
  const int lane = tid & 63, w = tid >> 6;
  const int wr = w >> 2, wc = w & 3;
  const int l15 = lane & 15, lq = lane >> 4;

  const int cpx = gridDim.x >> 3;
  const int L = (blockIdx.x & 7) * cpx + (blockIdx.x >> 3);
  const int bm = (L / nbn) * 128, bn = (L % nbn) * 256;

  const u16 *pa, *pb0, *pb1;
  {
    int p = tid * 16;
    int row = p >> 6;
    int lb = ((((p >> 4) & 3) ^ ((row >> 2) & 3)) << 4) | (p & 15);
    pa = A + (size_t)(bm + row) * lda + (lb >> 1);
    int r0 = p >> 6;
    int lb0 = ((((p >> 4) & 3) ^ ((r0 >> 2) & 3)) << 4) | (p & 15);
    pb0 = Bw + (size_t)(bn + r0) * ldb + (lb0 >> 1);
    int p1 = p + 8192;
    int r1 = p1 >> 6;
    int lb1 = ((((p1 >> 4) & 3) ^ ((r1 >> 2) & 3)) << 4) | (p1 & 15);
    pb1 = Bw + (size_t)(bn + r1) * ldb + (lb1 >> 1);
  }

  int offA[4], offB[4];
  #pragma unroll
  for (int mf = 0; mf < 4; ++mf) {
    int row = wr * 64 + mf * 16 + l15;
    offA[mf] = row * 32 + ((lq ^ ((row >> 2) & 3)) << 3);
  }
  #pragma unroll
  for (int j = 0; j < 4; ++j) {
    int row = wc * 64 + j * 16 + l15;
    offB[j] = row * 32 + ((lq ^ ((row >> 2) & 3)) << 3);
  }

  const int NS = K >> 5;

#define STAGE(s, sl) { \
    gload16(pa  + (s) * 32, &lds[(sl) * 4096 + w * 512]); \
    gload16(pb0 + (s) * 32, &lds[8192 + (sl) * 8192 + w * 512]); \
    gload16(pb1 + (s) * 32, &lds[8192 + (sl) * 8192 + w * 512 + 4096]); }

  f32x4 acc[4][4] = {};

  STAGE(0, 0);
  for (int h = 0; h < NS; ++h) {
    int nh = h + 1; if (nh > NS - 1) nh = NS - 1;
    STAGE(nh, (h + 1) & 1);
    WAIT_VM3();
    BAR();
    const int sa = (h & 1) * 4096, sb = 8192 + (h & 1) * 8192;
    bf16x8 af[4], bf4[4];
    #pragma unroll
    for (int i = 0; i < 4; ++i) af[i] = *(const bf16x8*)&lds[sa + offA[i]];
    #pragma unroll
    for (int j = 0; j < 4; ++j) bf4[j] = *(const bf16x8*)&lds[sb + offB[j]];
    WAIT_LGKM0();
    __builtin_amdgcn_s_setprio(1);
    #pragma unroll
    for (int mf = 0; mf < 4; ++mf)
      #pragma unroll
      for (int j = 0; j < 4; ++j)
        acc[mf][j] = mfma16(af[mf], bf4[j], acc[mf][j]);
    __builtin_amdgcn_s_setprio(0);
    BAR();
  }
  WAIT_VM0();

  #pragma unroll
  for (int q = 0; q < 4; ++q) {
    BAR();
    if (wr == (q >> 1)) {
      #pragma unroll
      for (int mi = 0; mi < 2; ++mi) {
        int mf = (q & 1) * 2 + mi;
        #pragma unroll
        for (int j = 0; j < 4; ++j)
          #pragma unroll
          for (int r = 0; r < 4; ++r) {
            int lrow = mi * 16 + lq * 4 + r;
            int col = wc * 64 + j * 16 + l15;
            int byt = (lrow * 1024 + col * 4) ^ (((lrow >> 2) & 3) << 6);
            *(float*)((char*)lds + byt) = acc[mf][j][r];
          }
      }
    }
    WAIT_LGKM0();
    BAR();
    #pragma unroll
    for (int k = 0; k < 2; ++k) {
      int c = tid + k * 512;
      int row = c >> 5, c32 = c & 31;
      int byt = (row * 1024 + c32 * 32) ^ (((row >> 2) & 3) << 6);
      f32x4 v0 = *(const f32x4*)((const char*)lds + byt);
      f32x4 v1 = *(const f32x4*)((const char*)lds + byt + 16);
      int gcol = bn + c32 * 8;
      size_t off = (size_t)(bm + q * 32 + row) * ldc + gcol;
      if (BIAS) {
        f32x4 bb0 = *(const f32x4*)(bias + gcol);
        f32x4 bb1 = *(const f32x4*)(bias + gcol + 4);
        #pragma unroll
        for (int i = 0; i < 4; ++i) { v0[i] += bb0[i]; v1[i] += bb1[i]; }
      }
      u16x8 ob;
      #pragma unroll
      for (int i = 0; i < 4; ++i) { ob[i] = f2b(v0[i]); ob[4 + i] = f2b(v1[i]); }
      *(u16x8*)(Cb + off) = ob;
    }
  }
#undef STAGE
}

// ===================== 256x256 8-phase pipelined bf16 NT GEMM (round-7) ==========
template<int BIAS, int ACC>
__global__ __launch_bounds__(512, 2) void gemm256(
    const u16* __restrict__ A, const u16* __restrict__ Bw,
    const float* __restrict__ bias, u16* __restrict__ Cb,
    int nbn, int K, int lda, int ldb, int ldc) {
  __shared__ u16 lds[65536];               // 128 KB
  const int tid = threadIdx.x;
  const int lane = tid & 63, w = tid >> 6;
  const int wr = w >> 2, wc = w & 3;
  const int l15 = lane & 15, lq = lane >> 4;

  const int cpx = gridDim.x >> 3;
  const int L = (blockIdx.x & 7) * cpx + (blockIdx.x >> 3);
  const int bm = (L / nbn) * 256, bn = (L % nbn) * 256;

  const u16 *pa0, *pa1, *pb0, *pb1;
  {
    int p0 = w * 1024 + lane * 16;
    int p1 = p0 + 8192;
    int lb0 = p0 ^ (((p0 >> 7) & 7) << 4);
    int lb1 = p1 ^ (((p1 >> 7) & 7) << 4);
    int r0 = (lb0 >> 7) + (((lb0 >> 6) & 1) << 7);
    int r1 = (lb1 >> 7) + (((lb1 >> 6) & 1) << 7);
    int c0 = (lb0 & 63) >> 1;
    int c1 = (lb1 & 63) >> 1;
    pa0 = A  + (size_t)(bm + r0) * lda + c0;
    pa1 = A  + (size_t)(bm + r1) * lda + c1;
    pb0 = Bw + (size_t)(bn + r0) * ldb + c0;
    pb1 = Bw + (size_t)(bn + r1) * ldb + c1;
  }
  const int dst = w * 512;

  int offA[8], offB[4];
  #pragma unroll
  for (int mf = 0; mf < 8; ++mf) {
    int rowp = mf * 16 + l15;
    offA[mf] = ((rowp * 128 + wr * 64 + lq * 16) ^ ((l15 & 7) << 4)) >> 1;
  }
  #pragma unroll
  for (int j = 0; j < 4; ++j) {
    int rB = wc * 64 + j * 16 + l15;
    int rowp = rB & 127, cg = rB >> 7;
    offB[j] = ((rowp * 128 + cg * 64 + lq * 16) ^ ((l15 & 7) << 4)) >> 1;
  }

  const int NK2 = K >> 5;
  const int NT  = K >> 6;

#define STAGEA(kh, slot) { \
    gload16(pa0 + (kh) * 32, &lds[(slot) * 8192 + dst]); \
    gload16(pa1 + (kh) * 32, &lds[(slot) * 8192 + dst + 4096]); }
#define STAGEB(kh, slot) { \
    gload16(pb0 + (kh) * 32, &lds[32768 + (slot) * 8192 + dst]); \
    gload16(pb1 + (kh) * 32, &lds[32768 + (slot) * 8192 + dst + 4096]); }
#define LDA4(slot, mh) { \
    _Pragma("unroll") for (int i = 0; i < 4; ++i) \
      af[i] = *(const bf16x8*)&lds[(slot) * 8192 + offA[(mh) * 4 + i]]; }
#define LDB4(slot) { \
    _Pragma("unroll") for (int j = 0; j < 4; ++j) \
      bf[j] = *(const bf16x8*)&lds[32768 + (slot) * 8192 + offB[j]]; }
#define MFMA16(mh) { \
    __builtin_amdgcn_s_setprio(1); \
    _Pragma("unroll") for (int i = 0; i < 4; ++i) \
      _Pragma("unroll") for (int j = 0; j < 4; ++j) \
        acc[(mh) * 4 + i][j] = mfma16(af[i], bf[j], acc[(mh) * 4 + i][j]); \
    __builtin_amdgcn_s_setprio(0); }

  f32x4 acc[8][4] = {};
  bf16x8 af[4], bf[4];

  STAGEA(0, 0); STAGEB(0, 0);
  STAGEA(1, 1); STAGEB(1, 1);
  STAGEA(2, 2); STAGEB(2, 2);
  WAIT_VM8();
  BAR();

  for (int t = 0; t < NT; ++t) {
    const int s0 = (2 * t) & 3, s1 = (2 * t + 1) & 3;
    int kh3 = 2 * t + 3; if (kh3 > NK2 - 1) kh3 = NK2 - 1;
    int kh4 = 2 * t + 4; if (kh4 > NK2 - 1) kh4 = NK2 - 1;
    const int w3 = (2 * t + 3) & 3, w4 = (2 * t + 4) & 3;

    LDB4(s0); LDA4(s0, 0);
    STAGEA(kh3, w3);
    BAR(); WAIT_LGKM0();
    MFMA16(0);
    BAR();

    LDA4(s0, 1);
    STAGEB(kh3, w3);
    BAR(); WAIT_LGKM0();
    MFMA16(1);
    WAIT_VM8();
    BAR();

    LDB4(s1); LDA4(s1, 0);
    STAGEA(kh4, w4);
    BAR(); WAIT_LGKM0();
    MFMA16(0);
    BAR();

    LDA4(s1, 1);
    STAGEB(kh4, w4);
    BAR(); WAIT_LGKM0();
    MFMA16(1);
    WAIT_VM8();
    BAR();
  }
  WAIT_VM0();

  #pragma unroll
  for (int h = 0; h < 2; ++h) {
    BAR();
    if (wr == h) {
      #pragma unroll
      for (int mf = 0; mf < 8; ++mf)
        #pragma unroll
        for (int j = 0; j < 4; ++j)
          #pragma unroll
          for (int r = 0; r < 4; ++r) {
            int row = mf * 16 + lq * 4 + r;
            int col = wc * 64 + j * 16 + l15;
            int byt = (row * 1024 + col * 4) ^ (((row >> 2) & 1) << 6);
            *(float*)((char*)lds + byt) = acc[mf][j][r];
          }
    }
    WAIT_LGKM0();
    BAR();
    #pragma unroll
    for (int k = 0; k < 8; ++k) {
      int c = tid + k * 512;
      int row = c >> 5, c32 = c & 31;
      int byt = (row * 1024 + c32 * 32) ^ (((row >> 2) & 1) << 6);
      f32x4 v0 = *(const f32x4*)((const char*)lds + byt);
      f32x4 v1 = *(const f32x4*)((const char*)lds + byt + 16);
      int gcol = bn + c32 * 8;
      size_t off = (size_t)(bm + h * 128 + row) * ldc + gcol;
      if (BIAS) {
        f32x4 bb0 = *(const f32x4*)(bias + gcol);
        f32x4 bb1 = *(const f32x4*)(bias + gcol + 4);
        #pragma unroll
        for (int i = 0; i < 4; ++i) { v0[i] += bb0[i]; v1[i] += bb1[i]; }
      }
      u16x8 ob;
      if (ACC) {
        u16x8 cr = *(const u16x8*)(Cb + off);
        #pragma unroll
        for (int i = 0; i < 4; ++i) {
          ob[i]     = f2b(v0[i] + b2f(cr[i]));
          ob[4 + i] = f2b(v1[i] + b2f(cr[4 + i]));
        }
      } else {
        #pragma unroll
        for (int i = 0; i < 4; ++i) { ob[i] = f2b(v0[i]); ob[4 + i] = f2b(v1[i]); }
      }
      *(u16x8*)(Cb + off) = ob;
    }
  }
#undef STAGEA
#undef STAGEB
#undef LDA4
#undef LDB4
#undef MFMA16
}

// ========== 128x512 GEMM + residual + LayerNorm fused (N=512 only) ==========
template<int BIAS, int F32OUT>
__global__ __launch_bounds__(512, 2) void gemm_ln(
    const u16* __restrict__ A, const u16* __restrict__ Bw,
    const float* __restrict__ bias,
    const u16* __restrict__ resid, const float* __restrict__ g,
    const float* __restrict__ bv,
    u16* outB, float* outF, int K, int lda, int ldb) {
  __shared__ u16 lds[40960];               // 80 KB
  const int tid = threadIdx.x;
  const int lane = tid & 63, w = tid >> 6;
  const int l15 = lane & 15, lq = lane >> 4;

  const int cpx = gridDim.x >> 3;
  const int L = (blockIdx.x & 7) * cpx + (blockIdx.x >> 3);
  const int bm = L * 128;

  const u16* pa;
  const u16* pb[4];
  {
    int p = tid * 16;
    int row = p >> 6;
    int lb = ((((p >> 4) & 3) ^ ((row >> 2) & 3)) << 4) | (p & 15);
    pa = A + (size_t)(bm + row) * lda + (lb >> 1);
    #pragma unroll
    for (int c = 0; c < 4; ++c) {
      int q = c * 8192 + tid * 16;
      int rowb = q >> 6;
      int lbb = ((((q >> 4) & 3) ^ ((rowb >> 2) & 3)) << 4) | (q & 15);
      pb[c] = Bw + (size_t)rowb * ldb + (lbb >> 1);
    }
  }

  int offA[8], offB[4];
  #pragma unroll
  for (int mf = 0; mf < 8; ++mf) {
    int row = mf * 16 + l15;
    offA[mf] = row * 32 + ((lq ^ ((row >> 2) & 3)) << 3);
  }
  #pragma unroll
  for (int j = 0; j < 4; ++j) {
    int row = w * 64 + j * 16 + l15;
    offB[j] = row * 32 + ((lq ^ ((row >> 2) & 3)) << 3);
  }

  const int NS = K >> 5;

#define STAGE(s, sl) { \
    gload16(pa + (s) * 32, &lds[(sl) * 4096 + w * 512]); \
    _Pragma("unroll") for (int c = 0; c < 4; ++c) \
      gload16(pb[c] + (s) * 32, &lds[8192 + (sl) * 16384 + c * 4096 + w * 512]); }

  f32x4 acc[8][4] = {};

  STAGE(0, 0);
  for (int h = 0; h < NS; ++h) {
    int nh = h + 1; if (nh > NS - 1) nh = NS - 1;
    STAGE(nh, (h + 1) & 1);
    WAIT_VM5();
    BAR();
    const int sa = (h & 1) * 4096, sb = 8192 + (h & 1) * 16384;
    bf16x8 af[8], bf4[4];
    #pragma unroll
    for (int i = 0; i < 8; ++i) af[i] = *(const bf16x8*)&lds[sa + offA[i]];
    #pragma unroll
    for (int j = 0; j < 4; ++j) bf4[j] = *(const bf16x8*)&lds[sb + offB[j]];
    WAIT_LGKM0();
    __builtin_amdgcn_s_setprio(1);
    #pragma unroll
    for (int mf = 0; mf < 8; ++mf)
      #pragma unroll
      for (int j = 0; j < 4; ++j)
        acc[mf][j] = mfma16(af[mf], bf4[j], acc[mf][j]);
    __builtin_amdgcn_s_setprio(0);
    BAR();
  }
  WAIT_VM0();

  float bias4[4] = {0.f, 0.f, 0.f, 0.f};
  if (BIAS) {
    #pragma unroll
    for (int j = 0; j < 4; ++j) bias4[j] = bias[w * 64 + j * 16 + l15];
  }
  const f32x4 gv0 = *(const f32x4*)(g + lane * 8);
  const f32x4 gv1 = *(const f32x4*)(g + lane * 8 + 4);
  const f32x4 bv0 = *(const f32x4*)(bv + lane * 8);
  const f32x4 bv1 = *(const f32x4*)(bv + lane * 8 + 4);

  #pragma unroll
  for (int q = 0; q < 4; ++q) {
    BAR();
    #pragma unroll
    for (int mi = 0; mi < 2; ++mi) {
      int mf = 2 * q + mi;
      #pragma unroll
      for (int j = 0; j < 4; ++j)
        #pragma unroll
        for (int r = 0; r < 4; ++r) {
          int lrow = mi * 16 + lq * 4 + r;
          int col = w * 64 + j * 16 + l15;
          int byt = (lrow * 2048 + col * 4) ^ (((lrow >> 2) & 3) << 6);
          *(float*)((char*)lds + byt) = acc[mf][j][r] + bias4[j];
        }
    }
    WAIT_LGKM0();
    BAR();
    #pragma unroll
    for (int rr = 0; rr < 4; ++rr) {
      int lrow = w * 4 + rr;
      int grow = bm + q * 32 + lrow;
      int byt = (lrow * 2048 + lane * 32) ^ (((lrow >> 2) & 3) << 6);
      f32x4 z0 = *(const f32x4*)((const char*)lds + byt);
      f32x4 z1 = *(const f32x4*)((const char*)lds + byt + 16);
      u16x8 av = *(const u16x8*)(resid + (size_t)grow * HD + lane * 8);
      float x[8];
      float s = 0.f;
      #pragma unroll
      for (int i = 0; i < 4; ++i) {
        x[i] = b2f(av[i]) + z0[i];
        x[4 + i] = b2f(av[4 + i]) + z1[i];
      }
      #pragma unroll
      for (int i = 0; i < 8; ++i) s += x[i];
      #pragma unroll
      for (int off = 32; off; off >>= 1) s += __shfl_xor(s, off);
      float m = s * (1.0f / HD);
      float vs = 0.f;
      #pragma unroll
      for (int i = 0; i < 8; ++i) { float d = x[i] - m; vs += d * d; }
      #pragma unroll
      for (int off = 32; off; off >>= 1) vs += __shfl_xor(vs, off);
      float rstd = rsqrtf(vs * (1.0f / HD) + 1e-5f);
      float o[8];
      #pragma unroll
      for (int i = 0; i < 4; ++i) {
        o[i]     = (x[i] - m) * rstd * gv0[i] + bv0[i];
        o[4 + i] = (x[4 + i] - m) * rstd * gv1[i] + bv1[i];
      }
      if (F32OUT) {
        f32x4 o0, o1;
        #pragma unroll
        for (int i = 0; i < 4; ++i) { o0[i] = o[i]; o1[i] = o[4 + i]; }
        *(f32x4*)(outF + (size_t)grow * HD + lane * 8) = o0;
        *(f32x4*)(outF + (size_t)grow * HD + lane * 8 + 4) = o1;
      } else {
        u16x8 ob;
        #pragma unroll
        for (int i = 0; i < 8; ++i) ob[i] = f2b(o[i]);
        *(u16x8*)(outB + (size_t)grow * HD + lane * 8) = ob;
      }
    }
  }
#undef STAGE
}

// ---------------- attention: one block per (b, head), S=64, DK=64 ----------------
template<int CAUSAL, int SAVEKV>
__global__ __launch_bounds__(256) void attn_kernel(
    u16* Q, const u16* __restrict__ Kb, const u16* __restrict__ Vb,
    const int* __restrict__ mask, int qld, int kvld, u16* __restrict__ kvdst) {
  __shared__ u16 Ks[64 * 72];
  __shared__ u16 Vt[64 * 72];
  __shared__ u16 Ps[4][16 * 72];
  const int bh = blockIdx.x;
  const int b = bh >> 3, h = bh & 7;
  const int h0 = h * 64;
  const int tid = threadIdx.x, lane = tid & 63, w = tid >> 6;
  const size_t qbase = (size_t)b * 64 * qld + h0;
  const size_t kbase = (size_t)b * 64 * kvld + h0;
  const int l15 = lane & 15, l16 = (lane >> 4) * 8;

  {
    int r = tid >> 2;
    int c = (tid & 3) * 16;
    const u16* ksrc = Kb + kbase + (size_t)r * kvld + c;
    u16x8 k0 = *(const u16x8*)ksrc;
    u16x8 k1 = *(const u16x8*)(ksrc + 8);
    *(u16x8*)&Ks[r * 72 + c]     = k0;
    *(u16x8*)&Ks[r * 72 + c + 8] = k1;
    const u16* vsrc = Vb + kbase + (size_t)r * kvld + c;
    u16x8 t0 = *(const u16x8*)vsrc;
    u16x8 t1 = *(const u16x8*)(vsrc + 8);
    #pragma unroll
    for (int i = 0; i < 8; ++i) {
      Vt[(c + i) * 72 + r]     = t0[i];
      Vt[(c + 8 + i) * 72 + r] = t1[i];
    }
    if (SAVEKV) {
      size_t db = (size_t)(b * 64 + r) * 1024 + h0 + c;
      *(u16x8*)(kvdst + db)       = k0;
      *(u16x8*)(kvdst + db + 8)   = k1;
      *(u16x8*)(kvdst + db + 512) = t0;
      *(u16x8*)(kvdst + db + 520) = t1;
    }
  }
  const int qrow = w * 16 + l15;
  const u16* qp = Q + qbase + (size_t)qrow * qld;
  bf16x8 qf0 = *(const bf16x8*)&qp[l16];
  bf16x8 qf1 = *(const bf16x8*)&qp[32 + l16];
  __syncthreads();

  f32x4 sc[4] = {};
  #pragma unroll
  for (int nf = 0; nf < 4; ++nf) {
    bf16x8 k0 = *(const bf16x8*)&Ks[(nf * 16 + l15) * 72 + l16];
    bf16x8 k1 = *(const bf16x8*)&Ks[(nf * 16 + l15) * 72 + 32 + l16];
    sc[nf] = mfma16(qf0, k0, sc[nf]);
    sc[nf] = mfma16(qf1, k1, sc[nf]);
  }
  int mk[4];
  #pragma unroll
  for (int nf = 0; nf < 4; ++nf) mk[nf] = mask[b * 64 + nf * 16 + l15];
  float pv[4][4];
  #pragma unroll
  for (int r = 0; r < 4; ++r) {
    int q = w * 16 + (lane >> 4) * 4 + r;
    #pragma unroll
    for (int nf = 0; nf < 4; ++nf) {
      int k = nf * 16 + l15;
      bool kp = (mk[nf] != 0);
      if (CAUSAL) kp = kp && (k <= q);
      pv[r][nf] = kp ? sc[nf][r] * 0.125f : -1e9f;
    }
  }
  #pragma unroll
  for (int r = 0; r < 4; ++r) {
    float mx = fmaxf(fmaxf(pv[r][0], pv[r][1]), fmaxf(pv[r][2], pv[r][3]));
    #pragma unroll
    for (int off = 1; off < 16; off <<= 1) mx = fmaxf(mx, __shfl_xor(mx, off));
    float sum = 0.f;
    #pragma unroll
    for (int nf = 0; nf < 4; ++nf) { pv[r][nf] = __expf(pv[r][nf] - mx); sum += pv[r][nf]; }
    #pragma unroll
    for (int off = 1; off < 16; off <<= 1) sum += __shfl_xor(sum, off);
    float inv = 1.0f / sum;
    #pragma unroll
    for (int nf = 0; nf < 4; ++nf) pv[r][nf] *= inv;
  }
  #pragma unroll
  for (int r = 0; r < 4; ++r) {
    int q = (lane >> 4) * 4 + r;
    #pragma unroll
    for (int nf = 0; nf < 4; ++nf)
      Ps[w][q * 72 + nf * 16 + l15] = f2b(pv[r][nf]);
  }
  f32x4 oacc[4] = {};
  #pragma unroll
  for (int kk = 0; kk < 2; ++kk) {
    bf16x8 pa = *(const bf16x8*)&Ps[w][l15 * 72 + kk * 32 + l16];
    #pragma unroll
    for (int df = 0; df < 4; ++df) {
      bf16x8 vf = *(const bf16x8*)&Vt[(df * 16 + l15) * 72 + kk * 32 + l16];
      oacc[df] = mfma16(pa, vf, oacc[df]);
    }
  }
  #pragma unroll
  for (int df = 0; df < 4; ++df) {
    int col = df * 16 + l15;
    #pragma unroll
    for (int r = 0; r < 4; ++r) {
      int t = w * 16 + (lane >> 4) * 4 + r;
      Q[qbase + (size_t)t * qld + col] = f2b(oacc[df][r]);
    }
  }
}

// ---------------- host side ----------------
extern "C" void kernel_launch(void* const* d_in, const int* in_sizes, int n_in,
                              void* d_out, int out_size, void* d_ws, size_t ws_size,
                              hipStream_t stream) {
  const int* src_ids    = (const int*)d_in[0];
  const int* tgt_ids    = (const int*)d_in[1];
  const int* src_mask   = (const int*)d_in[2];
  const int* tgt_mask   = (const int*)d_in[3];
  const float* src_emb  = (const float*)d_in[4];
  const float* tgt_emb  = (const float*)d_in[5];
  const float* enc_wq = (const float*)d_in[6];
  const float* enc_wk = (const float*)d_in[7];
  const float* enc_wv = (const float*)d_in[8];
  const float* enc_wo = (const float*)d_in[9];
  const float* enc_g  = (const float*)d_in[10];
  const float* enc_b  = (const float*)d_in[11];
  const float* fc1w = (const float*)d_in[12];
  const float* fc1b = (const float*)d_in[13];
  const float* fc2w = (const float*)d_in[14];
  const float* fc2b = (const float*)d_in[15];
  const float* mwq = (const float*)d_in[16];
  const float* mwk = (const float*)d_in[17];
  const float* mwv = (const float*)d_in[18];
  const float* mwo = (const float*)d_in[19];
  const float* cwq = (const float*)d_in[20];
  const float* cwo = (const float*)d_in[21];
  const float* dec_g = (const float*)d_in[22];
  const float* dec_b = (const float*)d_in[23];
  const float* dfw = (const float*)d_in[24];
  const float* dfb = (const float*)d_in[25];
  float* outF = (float*)d_out;
  u16* kvenc = (u16*)d_out;

  constexpr size_t SZ_PE  = (size_t)SLEN * HD * 4;
  constexpr size_t SZ_W   = (size_t)114 * EW * 2;
  constexpr size_t SZ_CUR = (size_t)TTOK * HD * 2;
  constexpr size_t SZ_QKV = (size_t)TTOK * 1536 * 2;
  constexpr size_t SZ_R   = (size_t)TTOK * FFD * 2;
  constexpr size_t SZ_Z2  = (size_t)TTOK * HD * 2;
  constexpr size_t NEED_SMALL = SZ_PE + SZ_W + SZ_CUR + SZ_QKV;
  constexpr size_t NEED_BIG   = SZ_PE + SZ_W + SZ_CUR + SZ_R + SZ_Z2;
  if (ws_size < NEED_SMALL) return;
  const bool big = (ws_size >= NEED_BIG);

  char* ws = (char*)d_ws;
  float* pe = (float*)ws;
  u16* W    = (u16*)(ws + SZ_PE);
  u16* cur  = (u16*)(ws + SZ_PE + SZ_W);
  u16* qkv  = (u16*)(ws + SZ_PE + SZ_W + SZ_CUR);
  u16* z2   = big ? (u16*)(ws + SZ_PE + SZ_W + SZ_CUR + SZ_R)
                  : qkv + (size_t)TTOK * 1024;

  dim3 blk(256), blk5(512);
  const unsigned int E = EW, S_E = 12 * EW, S_D = 7 * EW;
  u16* WD = W + (size_t)72 * EW;

  pe_kernel<<<128, blk, 0, stream>>>(pe);

  // merged weight conversion (identical layout to the original 13 launches)
  {
    WArgs wa;
    const float* srcs[13] = {enc_wq, enc_wk, enc_wv, enc_wo, fc1w, fc2w,
                             mwq, mwk, mwv, mwo, cwq, cwo, dfw};
    const unsigned long long dstoffs[13] = {
        0ull, (unsigned long long)E, 2ull * E, 3ull * E, 4ull * E, 8ull * E,
        72ull * E, 73ull * E, 74ull * E, 75ull * E, 76ull * E, 77ull * E, 78ull * E};
    const unsigned npls[13] = {E, E, E, E, 4 * E, 4 * E, E, E, E, E, E, E, E};
    const unsigned cumsE[14] = {0, 6, 12, 18, 24, 48, 72, 78, 84, 90, 96, 102, 108, 114};
    for (int t = 0; t < 13; ++t) {
      wa.src[t] = srcs[t];
      wa.dstoff[t] = dstoffs[t];
      wa.npl[t] = npls[t];
      wa.dstride[t] = (t < 6) ? S_E : S_D;
    }
    for (int t = 0; t < 14; ++t) wa.cum[t] = cumsE[t] * E;
    wconv_all<<<14592, blk, 0, stream>>>(wa, W);
  }

  // ---------------- encoder ----------------
  embed_kernel<<<8192, blk, 0, stream>>>(src_ids, src_emb, pe, cur);
  for (int l = 0; l < 6; ++l) {
    const u16* Wl = W + (size_t)l * S_E;
    const float* g  = enc_g + (size_t)l * HD;
    const float* bb = enc_b + (size_t)l * HD;
    const float* b1 = fc1b + (size_t)l * FFD;
    const float* b2 = fc2b + (size_t)l * HD;

    gemm128<0><<<1536, blk5, 0, stream>>>(cur, Wl, nullptr, qkv, 6, 512, 512, 512, 1536);
    if (l == 5)
      attn_kernel<0,1><<<4096, blk, 0, stream>>>(qkv, qkv + 512, qkv + 1024, src_mask, 1536, 1536, kvenc);
    else
      attn_kernel<0,0><<<4096, blk, 0, stream>>>(qkv, qkv + 512, qkv + 1024, src_mask, 1536, 1536, nullptr);
    if (big) {
      gemm_ln<0,0><<<256, blk5, 0, stream>>>(qkv, Wl + 3 * E, nullptr, cur, g, bb, cur, nullptr, 512, 1536, 512);
      gemm128<1><<<2048, blk5, 0, stream>>>(cur, Wl + 4 * E, b1, qkv, 8, 512, 512, 512, 2048);
      gemm_ln<1,0><<<256, blk5, 0, stream>>>(qkv, Wl + 8 * E, b2, cur, g, bb, cur, nullptr, 2048, 2048, 2048);
    } else {
      gemm256<0,0><<<256, blk5, 0, stream>>>(qkv, Wl + 3 * E, nullptr, qkv + 1024, 2, 512, 1536, 512, 1536);
      ln_kernel<0><<<8192, blk, 0, stream>>>(cur, qkv + 1024, 1536, g, bb, cur, nullptr);
      gemm256<1,0><<<512, blk5, 0, stream>>>(cur, Wl + 4 * E, b1,        qkv, 4, 512, 512, 512, 1024);
      gemm256<1,0><<<256, blk5, 0, stream>>>(qkv, Wl + 8 * E, b2,        z2,  2, 1024, 1024, 2048, 512);
      gemm256<1,0><<<512, blk5, 0, stream>>>(cur, Wl + 6 * E, b1 + 1024, qkv, 4, 512, 512, 512, 1024);
      gemm256<0,1><<<256, blk5, 0, stream>>>(qkv, Wl + 8 * E + 1024, nullptr, z2, 2, 1024, 1024, 2048, 512);
      ln_kernel<0><<<8192, blk, 0, stream>>>(cur, z2, 512, g, bb, cur, nullptr);
    }
  }

  // ---------------- decoder ----------------
  embed_kernel<<<8192, blk, 0, stream>>>(tgt_ids, tgt_emb, pe, cur);
  for (int l = 0; l < 6; ++l) {
    const u16* Wl = WD + (size_t)l * S_D;
    const float* g  = dec_g + (size_t)l * HD;
    const float* bb = dec_b + (size_t)l * HD;
    const float* fb = dfb + (size_t)l * HD;

    gemm128<0><<<1536, blk5, 0, stream>>>(cur, Wl, nullptr, qkv, 6, 512, 512, 512, 1536);
    attn_kernel<1,0><<<4096, blk, 0, stream>>>(qkv, qkv + 512, qkv + 1024, tgt_mask, 1536, 1536, nullptr);
    if (big) {
      gemm_ln<0,0><<<256, blk5, 0, stream>>>(qkv, Wl + 3 * E, nullptr, cur, g, bb, cur, nullptr, 512, 1536, 512);
      gemm128<0><<<512, blk5, 0, stream>>>(cur, Wl + 4 * E, nullptr, qkv, 2, 512, 512, 512, 1536);
      attn_kernel<1,0><<<4096, blk, 0, stream>>>(qkv, kvenc, kvenc + 512, tgt_mask, 1536, 1024, nullptr);
      gemm_ln<0,0><<<256, blk5, 0, stream>>>(qkv, Wl + 5 * E, nullptr, cur, g, bb, cur, nullptr, 512, 1536, 512);
      if (l == 5)
        gemm_ln<1,1><<<256, blk5, 0, stream>>>(cur, Wl + 6 * E, fb, cur, g, bb, nullptr, outF, 512, 512, 512);
      else
        gemm_ln<1,0><<<256, blk5, 0, stream>>>(cur, Wl + 6 * E, fb, cur, g, bb, cur, nullptr, 512, 512, 512);
    } else {
      gemm256<0,0><<<256, blk5, 0, stream>>>(qkv, Wl + 3 * E, nullptr, qkv + 1024, 2, 512, 1536, 512, 1536);
      ln_kernel<0><<<8192, blk, 0, stream>>>(cur, qkv + 1024, 1536, g, bb, cur, nullptr);
      gemm256<0,0><<<256, blk5, 0, stream>>>(cur, Wl + 4 * E, nullptr, qkv, 2, 512, 512, 512, 1536);
      attn_kernel<1,0><<<4096, blk, 0, stream>>>(qkv, kvenc, kvenc + 512, tgt_mask, 1536, 1024, nullptr);
      gemm256<0,0><<<256, blk5, 0, stream>>>(qkv, Wl + 5 * E, nullptr, qkv + 1024, 2, 512, 1536, 512, 1536);
      ln_kernel<0><<<8192, blk, 0, stream>>>(cur, qkv + 1024, 1536, g, bb, cur, nullptr);
      gemm256<1,0><<<256, blk5, 0, stream>>>(cur, Wl + 6 * E, fb, qkv, 2, 512, 512, 512, 512);
      if (l == 5)
        ln_kernel<1><<<8192, blk, 0, stream>>>(cur, qkv, 512, g, bb, nullptr, outF);
      else
        ln_kernel<0><<<8192, blk, 0, stream>>>(cur, qkv, 512, g, bb, cur, nullptr);
    }
  }
  (void)in_sizes; (void)n_in; (void)out_size;
}